// Round 11
// baseline (173.616 us; speedup 1.0000x reference)
//
#include <hip/hip_runtime.h>
#include <hip/hip_bf16.h>
#include <math.h>

#define N_NODES 2048
#define F_DIM   128
#define H_HEADS 4
#define B_BATCH 8
#define LEAKY   0.2f

typedef float f32x4 __attribute__((ext_vector_type(4)));
typedef float f32x2 __attribute__((ext_vector_type(2)));
typedef short bf16x8 __attribute__((ext_vector_type(8)));   // 8 bf16 = 4 VGPRs
typedef float f32x4a __attribute__((ext_vector_type(4)));   // mfma acc

__device__ __forceinline__ float tanh_fast(float x) {
    const float e = __expf(2.0f * x);
    return 1.0f - 2.0f / (e + 1.0f);
}
__device__ __forceinline__ unsigned short f2bf(float x) {   // RTNE f32->bf16
    unsigned u = __float_as_uint(x);
    u += 0x7FFFu + ((u >> 16) & 1u);
    return (unsigned short)(u >> 16);
}
__device__ __forceinline__ float bf2f(unsigned short s) {
    return __uint_as_float(((unsigned)s) << 16);
}

// ---------------- Kernel 0: bitpack A, layout [row][kch][s] ----------------
// byte for (row, kch, s) holds bits j <-> A[row][k = s*32 + kch*8 + j].
// tid covers k in [8t, 8t+8) -> kch = t&3, s = t>>2 -> offset (t&3)*64 + (t>>2).
__global__ __launch_bounds__(256) void gat_bitpack(const float* __restrict__ A,
                                                   unsigned char* __restrict__ maskb) {
    const int row = blockIdx.x;
    const int tid = threadIdx.x;
    const f32x4* Ar = (const f32x4*)(A + (size_t)row * N_NODES);
    const f32x4 a0 = Ar[tid * 2];
    const f32x4 a1 = Ar[tid * 2 + 1];
    unsigned b = 0;
    b |= (a0.x != 0.0f ? 1u : 0u) << 0;
    b |= (a0.y != 0.0f ? 1u : 0u) << 1;
    b |= (a0.z != 0.0f ? 1u : 0u) << 2;
    b |= (a0.w != 0.0f ? 1u : 0u) << 3;
    b |= (a1.x != 0.0f ? 1u : 0u) << 4;
    b |= (a1.y != 0.0f ? 1u : 0u) << 5;
    b |= (a1.z != 0.0f ? 1u : 0u) << 6;
    b |= (a1.w != 0.0f ? 1u : 0u) << 7;
    maskb[(size_t)row * 256 + (tid & 3) * 64 + (tid >> 2)] = (unsigned char)b;
}

// ---------------- Kernel 1: projections; packed [row][h] + planar [b][h][n] ----------------
__global__ __launch_bounds__(256) void gat_proj(const float* __restrict__ X,
                                                const float* __restrict__ wS,
                                                const float* __restrict__ wN,
                                                float* __restrict__ aSt,
                                                float* __restrict__ aNt,
                                                float* __restrict__ aNp) {
    const int wave = threadIdx.x >> 6;
    const int lane = threadIdx.x & 63;
    const int row  = blockIdx.x * 4 + wave;            // b*N + n
    const float* xr = X + (size_t)row * F_DIM;
    const float x0 = xr[lane];
    const float x1 = xr[lane + 64];
    float4 ps4, pn4;
    float* psv = (float*)&ps4;
    float* pnv = (float*)&pn4;
#pragma unroll
    for (int h = 0; h < H_HEADS; ++h) {
        float ps = x0 * wS[h * F_DIM + lane] + x1 * wS[h * F_DIM + 64 + lane];
        float pn = x0 * wN[h * F_DIM + lane] + x1 * wN[h * F_DIM + 64 + lane];
#pragma unroll
        for (int off = 32; off > 0; off >>= 1) {
            ps += __shfl_xor(ps, off);
            pn += __shfl_xor(pn, off);
        }
        psv[h] = ps;
        pnv[h] = pn;
    }
    if (lane == 0) {
        ((float4*)aSt)[row] = ps4;
        ((float4*)aNt)[row] = pn4;
        const int bb = row >> 11, nn = row & (N_NODES - 1);
#pragma unroll
        for (int h = 0; h < H_HEADS; ++h)
            aNp[((size_t)(bb * H_HEADS + h)) * N_NODES + nn] = pnv[h];
    }
}

// ---------------- Kernel 1b: per-(b,h) global max of a_neigh ----------------
__global__ __launch_bounds__(256) void gat_gmax(const float* __restrict__ aNt,
                                                float* __restrict__ gmax) {
    const int b = blockIdx.x;
    const int tid = threadIdx.x;
    const int lane = tid & 63;
    const int wv = tid >> 6;
    __shared__ float4 s_part[4];
    float4 m = make_float4(-1e30f, -1e30f, -1e30f, -1e30f);
    const float4* src = (const float4*)aNt + (size_t)b * N_NODES;
    for (int n = tid; n < N_NODES; n += 256) {
        const float4 v = src[n];
        m.x = fmaxf(m.x, v.x); m.y = fmaxf(m.y, v.y);
        m.z = fmaxf(m.z, v.z); m.w = fmaxf(m.w, v.w);
    }
#pragma unroll
    for (int off = 32; off > 0; off >>= 1) {
        m.x = fmaxf(m.x, __shfl_xor(m.x, off));
        m.y = fmaxf(m.y, __shfl_xor(m.y, off));
        m.z = fmaxf(m.z, __shfl_xor(m.z, off));
        m.w = fmaxf(m.w, __shfl_xor(m.w, off));
    }
    if (lane == 0) s_part[wv] = m;
    __syncthreads();
    if (tid == 0) {
        float4 r = s_part[0];
#pragma unroll
        for (int w = 1; w < 4; ++w) {
            r.x = fmaxf(r.x, s_part[w].x); r.y = fmaxf(r.y, s_part[w].y);
            r.z = fmaxf(r.z, s_part[w].z); r.w = fmaxf(r.w, s_part[w].w);
        }
        ((float4*)gmax)[b] = r;
    }
}

// ---------------- Kernel 1c: X -> fragment-ordered split-bf16 X^T ("XF") ----------------
// XF[b][s][pass][ft][kch][mrow][e]: element = X[b][k = s*32+kch*8+e][f = ft*16+mrow]
__global__ __launch_bounds__(256) void gat_xf(const float* __restrict__ X,
                                              unsigned short* __restrict__ XF) {
    const int bid = blockIdx.x;
    const int b = bid & 7;                              // batch-per-XCD
    const int s = bid >> 3;                             // 0..63
    const int tid = threadIdx.x;
    const float* Xb = X + (size_t)b * N_NODES * F_DIM;
    unsigned short* dst = XF + (size_t)(b * 64 + s) * 8192;
#pragma unroll
    for (int r = 0; r < 2; ++r) {
        const int u = r * 256 + tid;                    // 0..511
        const int mrow = u & 15, kc = (u >> 4) & 3, ft = u >> 6;
        const int f = ft * 16 + mrow;
        const int k0 = s * 32 + kc * 8;
        bf16x8 hv, lv;
#pragma unroll
        for (int e = 0; e < 8; ++e) {
            const float x = Xb[(size_t)(k0 + e) * F_DIM + f];
            const unsigned short hi = f2bf(x);
            hv[e] = (short)hi;
            lv[e] = (short)f2bf(x - bf2f(hi));
        }
        const int off = ((ft * 4 + kc) << 7) + (mrow << 3);
        *(bf16x8*)&dst[off] = hv;
        *(bf16x8*)&dst[4096 + off] = lv;
    }
}

// per-rowgroup P-gen: mask bits from MW at static shift (ss*8+j)
#define PGEN(MW, AS, MX, LS, FR)                                              \
    {                                                                         \
        unsigned q0_, q1_, q2_, q3_;                                          \
        {                                                                     \
            float ve, vo, pe, po;                                             \
            ve = (AS) + anv[0]; ve = fmaxf(ve, LEAKY * ve);                   \
            vo = (AS) + anv[1]; vo = fmaxf(vo, LEAKY * vo);                   \
            pe = __expf(ve - (MX)) * (float)((MW >> (ss * 8 + 0)) & 1u);      \
            po = __expf(vo - (MX)) * (float)((MW >> (ss * 8 + 1)) & 1u);      \
            asm("v_cvt_pk_bf16_f32 %0, %1, %2" : "=v"(q0_) : "v"(pe), "v"(po)); \
            ve = (AS) + anv[2]; ve = fmaxf(ve, LEAKY * ve);                   \
            vo = (AS) + anv[3]; vo = fmaxf(vo, LEAKY * vo);                   \
            pe = __expf(ve - (MX)) * (float)((MW >> (ss * 8 + 2)) & 1u);      \
            po = __expf(vo - (MX)) * (float)((MW >> (ss * 8 + 3)) & 1u);      \
            asm("v_cvt_pk_bf16_f32 %0, %1, %2" : "=v"(q1_) : "v"(pe), "v"(po)); \
            ve = (AS) + anv[4]; ve = fmaxf(ve, LEAKY * ve);                   \
            vo = (AS) + anv[5]; vo = fmaxf(vo, LEAKY * vo);                   \
            pe = __expf(ve - (MX)) * (float)((MW >> (ss * 8 + 4)) & 1u);      \
            po = __expf(vo - (MX)) * (float)((MW >> (ss * 8 + 5)) & 1u);      \
            asm("v_cvt_pk_bf16_f32 %0, %1, %2" : "=v"(q2_) : "v"(pe), "v"(po)); \
            ve = (AS) + anv[6]; ve = fmaxf(ve, LEAKY * ve);                   \
            vo = (AS) + anv[7]; vo = fmaxf(vo, LEAKY * vo);                   \
            pe = __expf(ve - (MX)) * (float)((MW >> (ss * 8 + 6)) & 1u);      \
            po = __expf(vo - (MX)) * (float)((MW >> (ss * 8 + 7)) & 1u);      \
            asm("v_cvt_pk_bf16_f32 %0, %1, %2" : "=v"(q3_) : "v"(pe), "v"(po)); \
        }                                                                     \
        LS += __uint_as_float(q0_ << 16) + __uint_as_float(q0_ & 0xffff0000u) \
            + __uint_as_float(q1_ << 16) + __uint_as_float(q1_ & 0xffff0000u) \
            + __uint_as_float(q2_ << 16) + __uint_as_float(q2_ & 0xffff0000u) \
            + __uint_as_float(q3_ << 16) + __uint_as_float(q3_ & 0xffff0000u); \
        union { unsigned u[4]; bf16x8 v; } U_;                                \
        U_.u[0] = q0_; U_.u[1] = q1_; U_.u[2] = q2_; U_.u[3] = q3_;           \
        FR = U_.v;                                                            \
    }

// ---------------- Kernel 2: dense masked-softmax + MFMA, 64 rows/wave ----------------
// grid = B * N/64 = 256 blocks; wave = head; each wave: 4 row-tiles share every B-read.
__global__ __launch_bounds__(256, 2) void gat_dense(const unsigned* __restrict__ maskw,
                                                    const float* __restrict__ aSt,
                                                    const float* __restrict__ aNp,
                                                    const float* __restrict__ gmax,
                                                    const unsigned short* __restrict__ XF,
                                                    float* __restrict__ out) {
    const int tid = threadIdx.x;
    const int bid = blockIdx.x;
    const int b = bid & 7;                              // batch-per-XCD
    const int Rbase = (bid >> 3) << 6;                  // 64-row block
    const int h = tid >> 6;                             // wave = head
    const int lane = tid & 63;
    const int mrow = lane & 15;
    const int kch = lane >> 4;

    __shared__ short ldsX[2][8192];                     // 2 x 16 KB fragment tile

    const float g = gmax[b * 4 + h];
    float aS0, aS1, aS2, aS3, m0, m1, m2, m3;
    {
        const int r0 = b * N_NODES + Rbase + mrow;
        aS0 = aSt[(size_t)r0 * 4 + h];
        aS1 = aSt[(size_t)(r0 + 16) * 4 + h];
        aS2 = aSt[(size_t)(r0 + 32) * 4 + h];
        aS3 = aSt[(size_t)(r0 + 48) * 4 + h];
        float v;
        v = aS0 + g; m0 = fmaxf(v, LEAKY * v);
        v = aS1 + g; m1 = fmaxf(v, LEAKY * v);
        v = aS2 + g; m2 = fmaxf(v, LEAKY * v);
        v = aS3 + g; m3 = fmaxf(v, LEAKY * v);
    }
    const float* aNh = aNp + ((size_t)(b * H_HEADS + h)) * N_NODES;
    const unsigned short* XFb = XF + (size_t)(b * 64) * 8192 + tid * 8;
    const unsigned mi0 = (unsigned)(b * N_NODES + Rbase + mrow) * 64 + kch * 16;
    // rowgroup r: + r*16*64 = r*1024 dwords

    f32x4a acc0[8], acc1[8], acc2[8], acc3[8];
#pragma unroll
    for (int ft = 0; ft < 8; ++ft) {
        acc0[ft] = (f32x4a){0.f, 0.f, 0.f, 0.f};
        acc1[ft] = (f32x4a){0.f, 0.f, 0.f, 0.f};
        acc2[ft] = (f32x4a){0.f, 0.f, 0.f, 0.f};
        acc3[ft] = (f32x4a){0.f, 0.f, 0.f, 0.f};
    }
    float ls0 = 0.f, ls1 = 0.f, ls2 = 0.f, ls3 = 0.f;

    // ---- prologue: masks s4=0, XF+aNp s=0, stage buf0 ----
    unsigned mw0 = maskw[mi0];
    unsigned mw1 = maskw[mi0 + 1024];
    unsigned mw2 = maskw[mi0 + 2048];
    unsigned mw3 = maskw[mi0 + 3072];
    {
        bf16x8 x0 = *(const bf16x8*)(XFb);
        bf16x8 x1 = *(const bf16x8*)(XFb + 2048);
        bf16x8 x2 = *(const bf16x8*)(XFb + 4096);
        bf16x8 x3 = *(const bf16x8*)(XFb + 6144);
        *(bf16x8*)&ldsX[0][tid * 8]        = x0;
        *(bf16x8*)&ldsX[0][tid * 8 + 2048] = x1;
        *(bf16x8*)&ldsX[0][tid * 8 + 4096] = x2;
        *(bf16x8*)&ldsX[0][tid * 8 + 6144] = x3;
    }
    f32x4 ana = *(const f32x4*)(aNh + kch * 8);
    f32x4 anb = *(const f32x4*)(aNh + kch * 8 + 4);
    __syncthreads();

    for (int s4 = 0; s4 < 16; ++s4) {
        unsigned nm0 = 0, nm1 = 0, nm2 = 0, nm3 = 0;
        if (s4 + 1 < 16) {                              // prefetch next mask dwords
            nm0 = maskw[mi0 + s4 + 1];
            nm1 = maskw[mi0 + 1024 + s4 + 1];
            nm2 = maskw[mi0 + 2048 + s4 + 1];
            nm3 = maskw[mi0 + 3072 + s4 + 1];
        }
#pragma unroll
        for (int ss = 0; ss < 4; ++ss) {
            const int s = (s4 << 2) + ss;
            const int cur = s & 1;
            const bool more = s < 63;
            bf16x8 nx0, nx1, nx2, nx3;
            f32x4 nna, nnb;
            if (more) {                                 // prefetch next XF tile + aNp
                const unsigned short* src = XFb + (size_t)(s + 1) * 8192;
                nx0 = *(const bf16x8*)(src);
                nx1 = *(const bf16x8*)(src + 2048);
                nx2 = *(const bf16x8*)(src + 4096);
                nx3 = *(const bf16x8*)(src + 6144);
                const int ko = (s + 1) * 32 + kch * 8;
                nna = *(const f32x4*)(aNh + ko);
                nnb = *(const f32x4*)(aNh + ko + 4);
            }
            const float anv[8] = {ana.x, ana.y, ana.z, ana.w,
                                  anb.x, anb.y, anb.z, anb.w};
            bf16x8 fr0, fr1, fr2, fr3;
            PGEN(mw0, aS0, m0, ls0, fr0);
            PGEN(mw1, aS1, m1, ls1, fr1);
            PGEN(mw2, aS2, m2, ls2, fr2);
            PGEN(mw3, aS3, m3, ls3, fr3);
#pragma unroll
            for (int ft = 0; ft < 8; ++ft) {            // hi pass: 1 read -> 4 MFMAs
                const bf16x8 bh = *(const bf16x8*)&ldsX[cur][ft * 512 + lane * 8];
                acc0[ft] = __builtin_amdgcn_mfma_f32_16x16x32_bf16(fr0, bh, acc0[ft], 0, 0, 0);
                acc1[ft] = __builtin_amdgcn_mfma_f32_16x16x32_bf16(fr1, bh, acc1[ft], 0, 0, 0);
                acc2[ft] = __builtin_amdgcn_mfma_f32_16x16x32_bf16(fr2, bh, acc2[ft], 0, 0, 0);
                acc3[ft] = __builtin_amdgcn_mfma_f32_16x16x32_bf16(fr3, bh, acc3[ft], 0, 0, 0);
            }
#pragma unroll
            for (int ft = 0; ft < 8; ++ft) {            // lo pass
                const bf16x8 bl = *(const bf16x8*)&ldsX[cur][4096 + ft * 512 + lane * 8];
                acc0[ft] = __builtin_amdgcn_mfma_f32_16x16x32_bf16(fr0, bl, acc0[ft], 0, 0, 0);
                acc1[ft] = __builtin_amdgcn_mfma_f32_16x16x32_bf16(fr1, bl, acc1[ft], 0, 0, 0);
                acc2[ft] = __builtin_amdgcn_mfma_f32_16x16x32_bf16(fr2, bl, acc2[ft], 0, 0, 0);
                acc3[ft] = __builtin_amdgcn_mfma_f32_16x16x32_bf16(fr3, bl, acc3[ft], 0, 0, 0);
            }
            if (more) {                                 // write next tile, rotate regs
                const int nb = cur ^ 1;
                *(bf16x8*)&ldsX[nb][tid * 8]        = nx0;
                *(bf16x8*)&ldsX[nb][tid * 8 + 2048] = nx1;
                *(bf16x8*)&ldsX[nb][tid * 8 + 4096] = nx2;
                *(bf16x8*)&ldsX[nb][tid * 8 + 6144] = nx3;
                ana = nna; anb = nnb;
            }
            __syncthreads();
        }
        mw0 = nm0; mw1 = nm1; mw2 = nm2; mw3 = nm3;
    }

    // ---- row sums: uniform over kch after xor-reduce; redistribute via shfl ----
    ls0 += __shfl_xor(ls0, 16); ls0 += __shfl_xor(ls0, 32);
    ls1 += __shfl_xor(ls1, 16); ls1 += __shfl_xor(ls1, 32);
    ls2 += __shfl_xor(ls2, 16); ls2 += __shfl_xor(ls2, 32);
    ls3 += __shfl_xor(ls3, 16); ls3 += __shfl_xor(ls3, 32);

    const size_t orow = (size_t)(b * N_NODES + Rbase);
#define EPI(ACC, LS, R)                                                       \
    {                                                                         \
        _Pragma("unroll")                                                     \
        for (int i = 0; i < 4; ++i) {                                         \
            const float inv = 1.0f / __shfl(LS, kch * 4 + i);                 \
            float* o = out + (orow + (R) * 16 + kch * 4 + i) * 512            \
                       + h * 128 + mrow;                                      \
            _Pragma("unroll")                                                 \
            for (int ft = 0; ft < 8; ++ft)                                    \
                __builtin_nontemporal_store(tanh_fast(ACC[ft][i] * inv),      \
                                            o + ft * 16);                     \
        }                                                                     \
    }
    EPI(acc0, ls0, 0)
    EPI(acc1, ls1, 1)
    EPI(acc2, ls2, 2)
    EPI(acc3, ls3, 3)
#undef EPI
}

// ---------------- Fallback (round-3 kernel): sparse gather path ----------------
__global__ __launch_bounds__(256, 6) void gat_main_fb(const float* __restrict__ X,
                                                      const float* __restrict__ A,
                                                      const float* __restrict__ aSt,
                                                      const float* __restrict__ aNt,
                                                      const float* __restrict__ gmax,
                                                      float* __restrict__ out) {
    const int tid = threadIdx.x;
    const int bid = blockIdx.x;
    const int row = ((bid & 7) << 11) | (bid >> 3);
    const int b = row >> 11;
    const int lane = tid & 63;
    const int wv = tid >> 6;

    __shared__ short  s_idx[N_NODES];
    __shared__ float4 s_p4[256];
    __shared__ int    s_off[256];
    __shared__ float  s_red[4 * 512];
    __shared__ int    s_wtot[4];
    __shared__ float  s_M[4];
    __shared__ float  s_sv[4];
    __shared__ float  s_scr[16];

    const f32x4* Arow = (const f32x4*)(A + (size_t)row * N_NODES);
    const f32x4 a0 = __builtin_nontemporal_load(Arow + tid * 2);
    const f32x4 a1 = __builtin_nontemporal_load(Arow + tid * 2 + 1);

    if (tid < 4) {
        const float sv = aSt[(size_t)row * 4 + tid];
        const float g = gmax[b * 4 + tid];
        float v = sv + g;
        v = fmaxf(v, LEAKY * v);
        s_M[tid] = v;
        s_sv[tid] = sv;
    }

    const float av[8] = {a0.x, a0.y, a0.z, a0.w, a1.x, a1.y, a1.z, a1.w};
    int c = 0;
#pragma unroll
    for (int k = 0; k < 8; ++k) c += (av[k] != 0.0f) ? 1 : 0;

    int incl = c;
#pragma unroll
    for (int d = 1; d < 64; d <<= 1) {
        const int u = __shfl_up(incl, d);
        if (lane >= d) incl += u;
    }
    if (lane == 63) s_wtot[wv] = incl;
    __syncthreads();
    int wbase = 0;
#pragma unroll
    for (int w = 0; w < 4; ++w) wbase += (w < wv) ? s_wtot[w] : 0;
    const int cnt = s_wtot[0] + s_wtot[1] + s_wtot[2] + s_wtot[3];
    int pos = wbase + (incl - c);
#pragma unroll
    for (int k = 0; k < 8; ++k) {
        if (av[k] != 0.0f) s_idx[pos++] = (short)(tid * 8 + k);
    }
    __syncthreads();

    float acc[4][4];
#pragma unroll
    for (int h = 0; h < 4; ++h)
#pragma unroll
        for (int fi = 0; fi < 4; ++fi) acc[h][fi] = 0.0f;
    float lsum[4] = {0.0f, 0.0f, 0.0f, 0.0f};

    const int jsub = tid >> 5;
    const int f4 = tid & 31;
    const char* XbB = (const char*)(X + (size_t)b * N_NODES * F_DIM) + (f4 << 4);
    const float4* aNb4 = (const float4*)aNt + (size_t)b * N_NODES;

    for (int base = 0; base < cnt; base += 256) {
        const int clen = min(256, cnt - base);
        if (tid < clen) {
            const int m = s_idx[base + tid];
            const float4 t = aNb4[m];
            const float tv[4] = {t.x, t.y, t.z, t.w};
            float4 p4;
            float* pp = (float*)&p4;
#pragma unroll
            for (int h = 0; h < H_HEADS; ++h) {
                float v = s_sv[h] + tv[h];
                v = fmaxf(v, LEAKY * v);
                const float p = __expf(v - s_M[h]);
                pp[h] = p;
                lsum[h] += p;
            }
            s_p4[tid] = p4;
            s_off[tid] = m << 9;
        }
        __syncthreads();
#pragma unroll 4
        for (int j = jsub; j < clen; j += 8) {
            const float4 pv = s_p4[j];
            const float4 xv = *(const float4*)(XbB + (unsigned)s_off[j]);
            const float pr[4] = {pv.x, pv.y, pv.z, pv.w};
#pragma unroll
            for (int h = 0; h < 4; ++h) {
                acc[h][0] = fmaf(pr[h], xv.x, acc[h][0]);
                acc[h][1] = fmaf(pr[h], xv.y, acc[h][1]);
                acc[h][2] = fmaf(pr[h], xv.z, acc[h][2]);
                acc[h][3] = fmaf(pr[h], xv.w, acc[h][3]);
            }
        }
        __syncthreads();
    }

#pragma unroll
    for (int h = 0; h < H_HEADS; ++h) {
        float v = lsum[h];
#pragma unroll
        for (int off = 32; off > 0; off >>= 1) v += __shfl_xor(v, off);
        if (lane == 0) s_scr[wv * 4 + h] = v;
    }
#pragma unroll
    for (int h = 0; h < 4; ++h)
#pragma unroll
        for (int fi = 0; fi < 4; ++fi)
            acc[h][fi] += __shfl_xor(acc[h][fi], 32);
    if (lane < 32) {
        float4* red4 = (float4*)s_red;
#pragma unroll
        for (int h = 0; h < 4; ++h)
            red4[wv * 128 + h * 32 + f4] =
                make_float4(acc[h][0], acc[h][1], acc[h][2], acc[h][3]);
    }
    __syncthreads();

    const int hf = tid * 2;
    const int h = tid >> 6;
    const float l = s_scr[h] + s_scr[4 + h] + s_scr[8 + h] + s_scr[12 + h];
    const float invl = 1.0f / l;
    float v0 = 0.0f, v1 = 0.0f;
#pragma unroll
    for (int w = 0; w < 4; ++w) {
        v0 += s_red[w * 512 + hf];
        v1 += s_red[w * 512 + hf + 1];
    }
    f32x2 o;
    o.x = tanh_fast(v0 * invl);
    o.y = tanh_fast(v1 * invl);
    __builtin_nontemporal_store(o, (f32x2*)&out[(size_t)row * 512 + hf]);
}

extern "C" void kernel_launch(void* const* d_in, const int* in_sizes, int n_in,
                              void* d_out, int out_size, void* d_ws, size_t ws_size,
                              hipStream_t stream) {
    const float* X  = (const float*)d_in[0];
    const float* A  = (const float*)d_in[1];
    const float* wS = (const float*)d_in[2];
    const float* wN = (const float*)d_in[3];
    float* out = (float*)d_out;

    const size_t nBNH = (size_t)B_BATCH * N_NODES * H_HEADS;    // 65536
    float* aSt = (float*)d_ws;
    float* aNt = aSt + nBNH;
    float* gmx = aNt + nBNH;
    float* aNp = gmx + B_BATCH * H_HEADS;
    unsigned short* XF = (unsigned short*)(aNp + nBNH);         // 8 MB
    unsigned char* maskb = (unsigned char*)(XF + (size_t)B_BATCH * 64 * 8192);  // 4 MB

    const size_t need = (nBNH * 3 + B_BATCH * H_HEADS) * 4
                        + (size_t)B_BATCH * 64 * 8192 * 2
                        + (size_t)B_BATCH * N_NODES * (N_NODES / 8);

    gat_proj<<<(B_BATCH * N_NODES) / 4, 256, 0, stream>>>(X, wS, wN, aSt, aNt, aNp);
    gat_gmax<<<B_BATCH, 256, 0, stream>>>(aNt, gmx);
    if (ws_size >= need) {
        gat_bitpack<<<B_BATCH * N_NODES, 256, 0, stream>>>(A, maskb);
        gat_xf<<<B_BATCH * 64, 256, 0, stream>>>(X, XF);
        gat_dense<<<B_BATCH * (N_NODES / 64), 256, 0, stream>>>((const unsigned*)maskb,
                                                                aSt, aNp, gmx, XF, out);
    } else {
        gat_main_fb<<<B_BATCH * N_NODES, 256, 0, stream>>>(X, A, aSt, aNt, gmx, out);
    }
}